// Round 4
// baseline (10.565 us; speedup 1.0000x reference)
//
#include <hip/hip_runtime.h>
#include <math.h>

// QuanvolutionHybrid — analytic collapse of the 4-qubit circuit.
// RZ = diagonal phase, CX = basis permutation, initial state real product
// => params drop out. Final bits (a,b,c^a,d^b) give per-patch features:
//   e0=cos(x0), e1=cos(x1), e2=cos(x0)cos(x2), e3=cos(x1)cos(x3)
// logits = feats @ W^T + b; out = log_softmax(logits).
//
// v4: 16 lanes per row / 4 rows per wave. LDS same-address broadcast across
// the 4 row-replicas -> 256 distinct bytes per ds_read_b128 (2 clk) => LDS
// cyc/row halves vs v2 (L=32). 4-step DPP reduce (within a DPP row of 16).
// 256 blocks x 256 threads: W staged half as often as v2.

#define BSZ 4096

// v += value-from-DPP-shuffled-v ; invalid-source lanes add 0 (bound_ctrl).
#define DPP_ADD(v, ctrl, rmask)                                              \
    v += __int_as_float(__builtin_amdgcn_update_dpp(                         \
        0, __float_as_int(v), (ctrl), (rmask), 0xf, true))

__global__ __launch_bounds__(256) void quanv_fused_v4(
    const float* __restrict__ x,     // [4096, 784]
    const float* __restrict__ W,     // [10, 784]
    const float* __restrict__ bias,  // [10]
    float* __restrict__ out)         // [4096, 10]
{
    __shared__ float sW[10 * 784];   // 31,360 B

    // Cooperative stage of W into LDS (coalesced float4).
    {
        const float4* Wv = (const float4*)W;
        float4* sWv = (float4*)sW;
        #pragma unroll
        for (int i = 0; i < 8; ++i) {
            int idx = threadIdx.x + i * 256;
            if (idx < 1960) sWv[idx] = Wv[idx];
        }
    }
    __syncthreads();

    const int tid  = threadIdx.x;
    const int wave = tid >> 6;           // 0..3
    const int lane = tid & 63;
    const int q    = lane >> 4;          // row within the quad (0..3)
    const int kl   = lane & 15;          // patch-lane within the 16-group
    const int row  = blockIdx.x * 16 + wave * 4 + q;   // < 4096

    const float* __restrict__ xr = x + row * 784;

    float acc[10];
    #pragma unroll
    for (int o = 0; o < 10; ++o) acc[o] = 0.f;

    // 196 patches over 16 lanes: k = t*16 + kl, t = 0..12 (t=12: kl<4 only).
    #pragma unroll
    for (int t = 0; t < 13; ++t) {
        const int k = t * 16 + kl;
        if (t < 12 || kl < 4) {
            const int r = k / 14;
            const int c = k - r * 14;
            const int base = r * 56 + c * 2;          // even -> 8B aligned
            const float2 a01 = *(const float2*)(xr + base);
            const float2 a23 = *(const float2*)(xr + base + 28);
            const float f0 = __cosf(a01.x);
            const float f1 = __cosf(a01.y);
            const float f2 = f0 * __cosf(a23.x);
            const float f3 = f1 * __cosf(a23.y);
            // All four 16-lane quads read identical addresses -> broadcast.
            const float* wk = sW + k * 4;
            #pragma unroll
            for (int o = 0; o < 10; ++o) {
                const float4 w4 = *(const float4*)(wk + o * 784);
                acc[o] = fmaf(f0, w4.x, acc[o]);
                acc[o] = fmaf(f1, w4.y, acc[o]);
                acc[o] = fmaf(f2, w4.z, acc[o]);
                acc[o] = fmaf(f3, w4.w, acc[o]);
            }
        }
    }

    // 16-lane DPP reduction per quad (row_shr 1/2/4/8, all within the DPP
    // row of 16). Totals land in lanes 15/31/47/63. VALU-only.
    #pragma unroll
    for (int o = 0; o < 10; ++o) {
        float v = acc[o];
        DPP_ADD(v, 0x111, 0xf);   // row_shr:1
        DPP_ADD(v, 0x112, 0xf);   // row_shr:2
        DPP_ADD(v, 0x114, 0xf);   // row_shr:4
        DPP_ADD(v, 0x118, 0xf);   // row_shr:8  -> lane 15 of each row of 16
        acc[o] = v;
    }

    // Finalize in the 4 total-holding lanes (15,31,47,63).
    if (kl == 15) {
        float lg[10];
        float m = -1e30f;
        #pragma unroll
        for (int o = 0; o < 10; ++o) {
            lg[o] = acc[o] + bias[o];
            m = fmaxf(m, lg[o]);
        }
        float s = 0.f;
        #pragma unroll
        for (int o = 0; o < 10; ++o) s += __expf(lg[o] - m);
        const float lse = __logf(s) + m;
        float* orow = out + row * 10;
        #pragma unroll
        for (int o = 0; o < 10; ++o) orow[o] = lg[o] - lse;
    }
}

extern "C" void kernel_launch(void* const* d_in, const int* in_sizes, int n_in,
                              void* d_out, int out_size, void* d_ws, size_t ws_size,
                              hipStream_t stream) {
    const float* x    = (const float*)d_in[0];
    // d_in[1] = params — provably irrelevant (phases/permutations only).
    const float* W    = (const float*)d_in[2];
    const float* bias = (const float*)d_in[3];
    float* out = (float*)d_out;

    dim3 grid(BSZ / 16);  // 256 blocks: 4 waves/block, 4 rows/wave
    dim3 block(256);
    quanv_fused_v4<<<grid, block, 0, stream>>>(x, W, bias, out);
}